// Round 6
// baseline (257.359 us; speedup 1.0000x reference)
//
#include <hip/hip_runtime.h>
#include <hip/hip_cooperative_groups.h>

namespace cg = cooperative_groups;

#define DIMV 16
#define NSTEP 4095      // 4096 - 1 increments
#define NC 128          // fine chunks (levels 1-3)
#define TSTEP 32        // fine chunk length
#define NC4 64          // coarse chunks for level-4 scan
#define T4 64           // coarse chunk length
#define SIG13 4368      // 16 + 256 + 4096
#define L4 65536        // 16^4
#define NBLK 256        // one block per CU

// 16-wide register vector as explicit float4s — never runtime-indexed (rule #20).
struct V16 { float4 a, b, c, d; };

#define EACH(OP) OP(a,x) OP(a,y) OP(a,z) OP(a,w) OP(b,x) OP(b,y) OP(b,z) OP(b,w) \
                 OP(c,x) OP(c,y) OP(c,z) OP(c,w) OP(d,x) OP(d,y) OP(d,z) OP(d,w)
#define EACHI(OP) OP(0,a,x) OP(1,a,y) OP(2,a,z) OP(3,a,w) \
                  OP(4,b,x) OP(5,b,y) OP(6,b,z) OP(7,b,w) \
                  OP(8,c,x) OP(9,c,y) OP(10,c,z) OP(11,c,w) \
                  OP(12,d,x) OP(13,d,y) OP(14,d,z) OP(15,d,w)

__device__ inline V16 ldv16(const float* p) {
    const float4* q = reinterpret_cast<const float4*>(p);
    V16 v; v.a = q[0]; v.b = q[1]; v.c = q[2]; v.d = q[3]; return v;
}
__device__ inline void stv16(float* p, const V16& v) {
    float4* q = reinterpret_cast<float4*>(p);
    q[0] = v.a; q[1] = v.b; q[2] = v.c; q[3] = v.d;
}
__device__ inline V16 zerov16() {
    V16 v; v.a = v.b = v.c = v.d = make_float4(0.f, 0.f, 0.f, 0.f); return v;
}

// ---------- Phase A: per-fine-chunk local signature (levels 1-3) + fused dx ----------
__device__ __forceinline__ void phaseA(int cb, int t, const float* __restrict__ x,
                                       float* __restrict__ dx,
                                       float* __restrict__ chunk_sig) {
    const int ia = t >> 4, ib = t & 15;
    float A1a = 0.f, A2 = 0.f;
    V16 A3 = zerov16();

    const int s0 = cb * TSTEP;
    const int s1 = (s0 + TSTEP < NSTEP) ? (s0 + TSTEP) : NSTEP;

    V16 xprev = ldv16(x + (size_t)s0 * DIMV);
    float xpa = x[(size_t)s0 * DIMV + ia];
    float xpb = x[(size_t)s0 * DIMV + ib];

    for (int s = s0; s < s1; ++s) {
        const float* nrow = x + (size_t)(s + 1) * DIMV;
        V16 xcur = ldv16(nrow);
        float xca = nrow[ia];
        float xcb = nrow[ib];
        V16 dxv;
#define SB(Q,C) dxv.Q.C = xcur.Q.C - xprev.Q.C;
        EACH(SB)
#undef SB
        float dxa = xca - xpa;
        float dxb = xcb - xpb;
        stv16(dx + (size_t)s * DIMV, dxv);

        float V2 = fmaf(dxb, fmaf(dxa, 1.f/6.f, 0.5f * A1a), A2);
        float h2 = fmaf(dxa, 0.5f, A1a);
#define CS(Q,C) A3.Q.C = fmaf(dxv.Q.C, V2, A3.Q.C);
        EACH(CS)
#undef CS
        A2 = fmaf(dxb, h2, A2);
        A1a += dxa;

        xprev = xcur; xpa = xca; xpb = xcb;
    }
    float* o = chunk_sig + (size_t)cb * SIG13;
    if (ib == 0) o[ia] = A1a;
    o[16 + t] = A2;
    stv16(o + 272 + t * 16, A3);
}

// ---------- Phase B: fused cascaded prefix (levels 1,2,3) ----------
// blk = a (0..15). P1/P2 computed redundantly per block into LDS; P3 slice for a.
// Writes compact coarse prefixes prefix_c[cb4] (even fine chunks) + final L1-3 to out13.
__device__ __forceinline__ void phaseB(int a, int t, const float* __restrict__ chunk_sig,
                                       float* __restrict__ prefix_c,
                                       float* __restrict__ out13,
                                       float (*s1s)[16], float (*p1s)[16],
                                       float (*p2s)[16]) {
    // load S1 of all fine chunks into LDS
    for (int base = 0; base < NC; base += 16) {
        int c = base + (t >> 4);
        s1s[c][t & 15] = chunk_sig[(size_t)c * SIG13 + (t & 15)];
    }
    __syncthreads();
    // P1 exclusive prefix (threads 0..15), redundant per block
    if (t < 16) {
        float p = 0.f;
        for (int c = 0; c < NC; ++c) {
            p1s[c][t] = p;
            if (a == 0 && !(c & 1)) prefix_c[(size_t)(c >> 1) * SIG13 + t] = p;
            p += s1s[c][t];
        }
        if (a == 0) out13[t] = p;
    }
    __syncthreads();
    // P2 exclusive prefix, redundant all 256 lanes; lanes in the a-slice record to LDS
    {
        const int aa = t >> 4, bb = t & 15;
        float pl0 = chunk_sig[0ul * SIG13 + 16 + t];
        float pl1 = chunk_sig[1ul * SIG13 + 16 + t];
        float pl2 = chunk_sig[2ul * SIG13 + 16 + t];
        float pl3 = chunk_sig[3ul * SIG13 + 16 + t];
        float pl4 = chunk_sig[4ul * SIG13 + 16 + t];
        float pl5 = chunk_sig[5ul * SIG13 + 16 + t];
        float pl6 = chunk_sig[6ul * SIG13 + 16 + t];
        float pl7 = chunk_sig[7ul * SIG13 + 16 + t];
        float p = 0.f;
        for (int cb2 = 0; cb2 < NC; cb2 += 8) {
#define STEP2(J) { int c = cb2 + J; \
            if (aa == a) p2s[c][bb] = p; \
            if (a == 0 && !(c & 1)) prefix_c[(size_t)(c >> 1) * SIG13 + 16 + t] = p; \
            p = fmaf(p1s[c][aa], s1s[c][bb], p + pl##J); \
            int cn = c + 8; \
            if (cn < NC) pl##J = chunk_sig[(size_t)cn * SIG13 + 16 + t]; }
            STEP2(0) STEP2(1) STEP2(2) STEP2(3) STEP2(4) STEP2(5) STEP2(6) STEP2(7)
#undef STEP2
        }
        if (a == 0) out13[16 + t] = p;
    }
    __syncthreads();
    // P3 for slice a: p += L3 + P1_a*L2 + P2_(a,k)*S1, 8-deep prefetch on global streams
    {
        const int c3 = t & 15, k = t >> 4;
        const size_t off3 = 272 + (size_t)a * 256 + t;
#define LD3(J, C) \
        float l3_##J = chunk_sig[(size_t)(C) * SIG13 + off3]; \
        float l2_##J = chunk_sig[(size_t)(C) * SIG13 + 16 + t];
        LD3(0,0) LD3(1,1) LD3(2,2) LD3(3,3) LD3(4,4) LD3(5,5) LD3(6,6) LD3(7,7)
#undef LD3
        float p = 0.f;
        for (int cb2 = 0; cb2 < NC; cb2 += 8) {
#define STEP3(J) { int c = cb2 + J; \
            if (!(c & 1)) prefix_c[(size_t)(c >> 1) * SIG13 + off3] = p; \
            p = p + l3_##J + fmaf(p1s[c][a], l2_##J, p2s[c][k] * s1s[c][c3]); \
            int cn = c + 8; \
            if (cn < NC) { \
                l3_##J = chunk_sig[(size_t)cn * SIG13 + off3]; \
                l2_##J = chunk_sig[(size_t)cn * SIG13 + 16 + t]; } }
            STEP3(0) STEP3(1) STEP3(2) STEP3(3) STEP3(4) STEP3(5) STEP3(6) STEP3(7)
#undef STEP3
        }
        out13[off3] = p;
    }
}

// ---------- Phase C: level-4 accumulation, d-split (proven R3 variant) ----------
__device__ __forceinline__ void phaseC(int cb, int g, int t,
                                       const float* __restrict__ dx,
                                       const float* __restrict__ prefix_c,
                                       float* __restrict__ partials) {
    const int ia = t >> 4, ib = t & 15;
    const float* P = prefix_c + (size_t)cb * SIG13;
    float A1a = P[ia];
    float A2 = P[16 + t];
    V16 A3 = ldv16(P + 272 + t * 16);
    V16 ac0 = zerov16(), ac1 = zerov16(), ac2 = zerov16(), ac3 = zerov16();

    const int s0 = cb * T4;
    const int s1 = (s0 + T4 < NSTEP) ? (s0 + T4) : NSTEP;
    for (int s = s0; s < s1; ++s) {
        const float* row = dx + (size_t)s * DIMV;
        V16 dxv = ldv16(row);
        float dxa = row[ia];
        float dxb = row[ib];
        float4 qd = *reinterpret_cast<const float4*>(row + g * 4);

        float U2 = fmaf(dxb, fmaf(dxa, 1.f/24.f, A1a * (1.f/6.f)), 0.5f * A2);
        float V2 = fmaf(dxb, fmaf(dxa, 1.f/6.f, A1a * 0.5f), A2);
        float h2 = fmaf(dxa, 0.5f, A1a);
#define S4(Q,C) { float u3 = fmaf(dxv.Q.C, U2, A3.Q.C); \
                  ac0.Q.C = fmaf(u3, qd.x, ac0.Q.C); \
                  ac1.Q.C = fmaf(u3, qd.y, ac1.Q.C); \
                  ac2.Q.C = fmaf(u3, qd.z, ac2.Q.C); \
                  ac3.Q.C = fmaf(u3, qd.w, ac3.Q.C); \
                  A3.Q.C = fmaf(dxv.Q.C, V2, A3.Q.C); }
        EACH(S4)
#undef S4
        A2 = fmaf(dxb, h2, A2);
        A1a += dxa;
    }
    float* o = partials + (size_t)cb * L4 + t * 256 + g * 4;
#define STO(J,Q,C) *reinterpret_cast<float4*>(o + (J)*16) = \
                       make_float4(ac0.Q.C, ac1.Q.C, ac2.Q.C, ac3.Q.C);
    EACHI(STO)
#undef STO
}

// ---------- Phase D: reduce partials over chunks ----------
__device__ __forceinline__ void phaseD(int tid, const float* __restrict__ partials,
                                       float* __restrict__ out4) {
    float s = 0.f;
#pragma unroll 8
    for (int c = 0; c < NC4; ++c) s += partials[(size_t)c * L4 + tid];
    out4[tid] = s;
}

// ---------- fused cooperative kernel ----------
__global__ __launch_bounds__(256, 1) void k_fused(const float* __restrict__ x,
                                                  float* __restrict__ dx,
                                                  float* __restrict__ chunk_sig,
                                                  float* __restrict__ prefix_c,
                                                  float* __restrict__ partials,
                                                  float* __restrict__ out) {
    __shared__ float s1s[NC][16];
    __shared__ float p1s[NC][16];
    __shared__ float p2s[NC][16];
    const int blk = blockIdx.x;
    const int t = threadIdx.x;
    cg::grid_group grid = cg::this_grid();

    if (blk < NC) phaseA(blk, t, x, dx, chunk_sig);
    __threadfence();
    grid.sync();

    if (blk < 16) phaseB(blk, t, chunk_sig, prefix_c, out, s1s, p1s, p2s);
    __threadfence();
    grid.sync();

    phaseC(blk >> 2, blk & 3, t, dx, prefix_c, partials);
    __threadfence();
    grid.sync();

    phaseD(blk * 256 + t, partials, out + SIG13);
}

extern "C" void kernel_launch(void* const* d_in, const int* in_sizes, int n_in,
                              void* d_out, int out_size, void* d_ws, size_t ws_size,
                              hipStream_t stream) {
    const float* x = (const float*)d_in[0];
    float* out = (float*)d_out;
    float* ws = (float*)d_ws;

    float* dx = ws;                                     // 65536 floats
    float* chunk_sig = ws + 65536;                      // NC * SIG13
    float* prefix_c = chunk_sig + (size_t)NC * SIG13;   // NC4 * SIG13 (coarse)
    float* partials = prefix_c + (size_t)NC4 * SIG13;   // NC4 * L4

    void* args[] = {(void*)&x, (void*)&dx, (void*)&chunk_sig,
                    (void*)&prefix_c, (void*)&partials, (void*)&out};
    hipLaunchCooperativeKernel((const void*)k_fused, dim3(NBLK), dim3(256),
                               args, 0, stream);
}

// Round 7
// 61.659 us; speedup vs baseline: 4.1739x; 4.1739x over previous
//
#include <hip/hip_runtime.h>

#define DIMV 16
#define NSTEP 4095      // 4096 - 1 increments
#define NC 64           // chunks
#define TSTEP 64        // chunk length
#define SIG13 4368      // 16 + 256 + 4096
#define L4 65536        // 16^4

// 16-wide register vector as explicit float4s — never runtime-indexed (rule #20).
struct V16 { float4 a, b, c, d; };

#define EACH(OP) OP(a,x) OP(a,y) OP(a,z) OP(a,w) OP(b,x) OP(b,y) OP(b,z) OP(b,w) \
                 OP(c,x) OP(c,y) OP(c,z) OP(c,w) OP(d,x) OP(d,y) OP(d,z) OP(d,w)

__device__ inline V16 ldv16(const float* p) {
    const float4* q = reinterpret_cast<const float4*>(p);
    V16 v; v.a = q[0]; v.b = q[1]; v.c = q[2]; v.d = q[3]; return v;
}
__device__ inline void stv16(float* p, const V16& v) {
    float4* q = reinterpret_cast<float4*>(p);
    q[0] = v.a; q[1] = v.b; q[2] = v.c; q[3] = v.d;
}
__device__ inline V16 zerov16() {
    V16 v; v.a = v.b = v.c = v.d = make_float4(0.f, 0.f, 0.f, 0.f); return v;
}

// ------------- per-chunk LOCAL signature (levels 1-3) + fused dx -------------
// 1-row-ahead prefetch: compute with xcur while xnext loads.
__global__ __launch_bounds__(256, 1) void k_chunk_sig(const float* __restrict__ x,
                                                      float* __restrict__ dx,
                                                      float* __restrict__ chunk_sig) {
    const int cb = blockIdx.x;
    const int t = threadIdx.x;
    const int ia = t >> 4, ib = t & 15;
    float A1a = 0.f, A2 = 0.f;
    V16 A3 = zerov16();

    const int s0 = cb * TSTEP;
    const int s1 = (s0 + TSTEP < NSTEP) ? (s0 + TSTEP) : NSTEP;

    const float* r0 = x + (size_t)s0 * DIMV;
    const float* r1 = x + (size_t)(s0 + 1) * DIMV;
    V16 xprev = ldv16(r0);
    float xpa = r0[ia], xpb = r0[ib];
    V16 xcur = ldv16(r1);
    float xca = r1[ia], xcb = r1[ib];

    for (int s = s0; s < s1; ++s) {
        // prefetch row s+2 (clamped; dead at tail)
        int sp = (s + 2 <= NSTEP) ? (s + 2) : NSTEP;
        const float* rn = x + (size_t)sp * DIMV;
        V16 xnext = ldv16(rn);
        float xna = rn[ia], xnb = rn[ib];

        V16 dxv;
#define SB(Q,C) dxv.Q.C = xcur.Q.C - xprev.Q.C;
        EACH(SB)
#undef SB
        float dxa = xca - xpa;
        float dxb = xcb - xpb;
        stv16(dx + (size_t)s * DIMV, dxv);

        float V2 = fmaf(dxb, fmaf(dxa, 1.f/6.f, 0.5f * A1a), A2);
        float h2 = fmaf(dxa, 0.5f, A1a);
#define CS(Q,C) A3.Q.C = fmaf(dxv.Q.C, V2, A3.Q.C);
        EACH(CS)
#undef CS
        A2 = fmaf(dxb, h2, A2);
        A1a += dxa;

        xprev = xcur; xpa = xca; xpb = xcb;
        xcur = xnext; xca = xna; xcb = xnb;
    }
    float* o = chunk_sig + (size_t)cb * SIG13;
    if (ib == 0) o[ia] = A1a;
    o[16 + t] = A2;
    stv16(o + 272 + t * 16, A3);
}

// ------------- fused cascaded prefix (levels 1,2,3) — R6-verified math -------------
// 16 blocks (a = blockIdx). P1/P2 computed redundantly per block into LDS;
// P3 slice for a. Writes exclusive prefixes + final L1-3 to out13.
__global__ __launch_bounds__(256, 1) void k_prefixB(const float* __restrict__ chunk_sig,
                                                    float* __restrict__ prefix_sig,
                                                    float* __restrict__ out13) {
    __shared__ float s1s[NC][16];
    __shared__ float p1s[NC][16];
    __shared__ float p2s[NC][16];
    const int a = blockIdx.x;
    const int t = threadIdx.x;

    // load S1 of all chunks into LDS
    for (int base = 0; base < NC; base += 16) {
        int c = base + (t >> 4);
        s1s[c][t & 15] = chunk_sig[(size_t)c * SIG13 + (t & 15)];
    }
    __syncthreads();
    // P1 exclusive prefix (threads 0..15), redundant per block
    if (t < 16) {
        float p = 0.f;
        for (int c = 0; c < NC; ++c) {
            p1s[c][t] = p;
            if (a == 0) prefix_sig[(size_t)c * SIG13 + t] = p;
            p += s1s[c][t];
        }
        if (a == 0) out13[t] = p;
    }
    __syncthreads();
    // P2 exclusive prefix, redundant all lanes; a-slice recorded to LDS
    {
        const int aa = t >> 4, bb = t & 15;
        float pl0 = chunk_sig[0ul * SIG13 + 16 + t];
        float pl1 = chunk_sig[1ul * SIG13 + 16 + t];
        float pl2 = chunk_sig[2ul * SIG13 + 16 + t];
        float pl3 = chunk_sig[3ul * SIG13 + 16 + t];
        float pl4 = chunk_sig[4ul * SIG13 + 16 + t];
        float pl5 = chunk_sig[5ul * SIG13 + 16 + t];
        float pl6 = chunk_sig[6ul * SIG13 + 16 + t];
        float pl7 = chunk_sig[7ul * SIG13 + 16 + t];
        float p = 0.f;
        for (int cb2 = 0; cb2 < NC; cb2 += 8) {
#define STEP2(J) { int c = cb2 + J; \
            if (aa == a) p2s[c][bb] = p; \
            if (a == 0) prefix_sig[(size_t)c * SIG13 + 16 + t] = p; \
            p = fmaf(p1s[c][aa], s1s[c][bb], p + pl##J); \
            int cn = c + 8; \
            if (cn < NC) pl##J = chunk_sig[(size_t)cn * SIG13 + 16 + t]; }
            STEP2(0) STEP2(1) STEP2(2) STEP2(3) STEP2(4) STEP2(5) STEP2(6) STEP2(7)
#undef STEP2
        }
        if (a == 0) out13[16 + t] = p;
    }
    __syncthreads();
    // P3 for slice a, 8-deep prefetch on the two global streams
    {
        const int c3 = t & 15, k = t >> 4;
        const size_t off3 = 272 + (size_t)a * 256 + t;
#define LD3(J, C) \
        float l3_##J = chunk_sig[(size_t)(C) * SIG13 + off3]; \
        float l2_##J = chunk_sig[(size_t)(C) * SIG13 + 16 + t];
        LD3(0,0) LD3(1,1) LD3(2,2) LD3(3,3) LD3(4,4) LD3(5,5) LD3(6,6) LD3(7,7)
#undef LD3
        float p = 0.f;
        for (int cb2 = 0; cb2 < NC; cb2 += 8) {
#define STEP3(J) { int c = cb2 + J; \
            prefix_sig[(size_t)c * SIG13 + off3] = p; \
            p = p + l3_##J + fmaf(p1s[c][a], l2_##J, p2s[c][k] * s1s[c][c3]); \
            int cn = c + 8; \
            if (cn < NC) { \
                l3_##J = chunk_sig[(size_t)cn * SIG13 + off3]; \
                l2_##J = chunk_sig[(size_t)cn * SIG13 + 16 + t]; } }
            STEP3(0) STEP3(1) STEP3(2) STEP3(3) STEP3(4) STEP3(5) STEP3(6) STEP3(7)
#undef STEP3
        }
        out13[off3] = p;
    }
}

// ------------- level-4 accumulation: j-pair split + row prefetch -------------
// block (cb, h): chunk cb (64 steps), j-pair h. VGPR ~85 -> 2 blocks/CU, no spill.
template <bool ATOMIC>
__global__ __launch_bounds__(256, 2) void k_scan4(const float* __restrict__ dx,
                                                  const float* __restrict__ prefix_sig,
                                                  float* __restrict__ dst) {
    const int cb = blockIdx.x;   // 0..NC-1
    const int h = blockIdx.y;    // 0..7 : j-pair
    const int t = threadIdx.x;
    const int ia = t >> 4, ib = t & 15;

    const float* P = prefix_sig + (size_t)cb * SIG13;
    float A1a = P[ia];
    float A2 = P[16 + t];
    float2 A3p = *reinterpret_cast<const float2*>(P + 272 + t * 16 + h * 2);
    V16 ac0 = zerov16(), ac1 = zerov16();

    const int s0 = cb * TSTEP;
    const int s1 = (s0 + TSTEP < NSTEP) ? (s0 + TSTEP) : NSTEP;

    const float* r0 = dx + (size_t)s0 * DIMV;
    V16 cur = ldv16(r0);
    float ca = r0[ia], cbv = r0[ib];
    float2 cj = *reinterpret_cast<const float2*>(r0 + h * 2);

    for (int s = s0; s < s1; ++s) {
        // prefetch next row (clamped; dead at tail)
        int sp = (s + 1 < s1) ? (s + 1) : s;
        const float* rn = dx + (size_t)sp * DIMV;
        V16 nxt = ldv16(rn);
        float na = rn[ia], nb = rn[ib];
        float2 nj = *reinterpret_cast<const float2*>(rn + h * 2);

        float U2 = fmaf(cbv, fmaf(ca, 1.f/24.f, A1a * (1.f/6.f)), 0.5f * A2);
        float V2 = fmaf(cbv, fmaf(ca, 1.f/6.f, A1a * 0.5f), A2);
        float h2 = fmaf(ca, 0.5f, A1a);
        float u30 = fmaf(cj.x, U2, A3p.x);
        float u31 = fmaf(cj.y, U2, A3p.y);
#define AC(Q,C) { ac0.Q.C = fmaf(u30, cur.Q.C, ac0.Q.C); \
                  ac1.Q.C = fmaf(u31, cur.Q.C, ac1.Q.C); }
        EACH(AC)
#undef AC
        A3p.x = fmaf(cj.x, V2, A3p.x);
        A3p.y = fmaf(cj.y, V2, A3p.y);
        A2 = fmaf(cbv, h2, A2);
        A1a += ca;

        cur = nxt; ca = na; cbv = nb; cj = nj;
    }

    if (ATOMIC) {
        float* o = dst + t * 256 + (h * 2) * 16;
#define STA(Q,C,K) atomicAdd(o + (K), ac0.Q.C); atomicAdd(o + 16 + (K), ac1.Q.C);
        STA(a,x,0) STA(a,y,1) STA(a,z,2) STA(a,w,3)
        STA(b,x,4) STA(b,y,5) STA(b,z,6) STA(b,w,7)
        STA(c,x,8) STA(c,y,9) STA(c,z,10) STA(c,w,11)
        STA(d,x,12) STA(d,y,13) STA(d,z,14) STA(d,w,15)
#undef STA
    } else {
        float* o = dst + (size_t)cb * L4 + t * 256 + (h * 2) * 16;
        stv16(o, ac0);
        stv16(o + 16, ac1);
    }
}

// ------------- sum per-chunk level-4 partials (float2, 128 blocks) -------------
__global__ __launch_bounds__(256) void k_reduce4(const float* __restrict__ partials,
                                                 float* __restrict__ out4) {
    const int i2 = blockIdx.x * 256 + threadIdx.x;  // 0..32767 float2 slots
    const float2* p2 = reinterpret_cast<const float2*>(partials);
    float2 s = make_float2(0.f, 0.f);
#pragma unroll 8
    for (int c = 0; c < NC; ++c) {
        float2 v = p2[(size_t)c * (L4 / 2) + i2];
        s.x += v.x; s.y += v.y;
    }
    reinterpret_cast<float2*>(out4)[i2] = s;
}

extern "C" void kernel_launch(void* const* d_in, const int* in_sizes, int n_in,
                              void* d_out, int out_size, void* d_ws, size_t ws_size,
                              hipStream_t stream) {
    const float* x = (const float*)d_in[0];
    float* out = (float*)d_out;
    float* ws = (float*)d_ws;

    float* dx = ws;                                     // 65536 floats
    float* chunk_sig = ws + 65536;                      // NC * SIG13
    float* prefix_sig = chunk_sig + (size_t)NC * SIG13; // NC * SIG13
    float* partials = prefix_sig + (size_t)NC * SIG13;  // NC * L4
    const size_t need_bytes =
        ((size_t)65536 + 2ull * NC * SIG13 + (size_t)NC * L4) * sizeof(float);

    k_chunk_sig<<<dim3(NC), dim3(256), 0, stream>>>(x, dx, chunk_sig);
    k_prefixB<<<dim3(16), dim3(256), 0, stream>>>(chunk_sig, prefix_sig, out);

    if (ws_size >= need_bytes) {
        k_scan4<false><<<dim3(NC, 8), dim3(256), 0, stream>>>(dx, prefix_sig, partials);
        k_reduce4<<<dim3(128), dim3(256), 0, stream>>>(partials, out + SIG13);
    } else {
        hipMemsetAsync(out + SIG13, 0, (size_t)L4 * sizeof(float), stream);
        k_scan4<true><<<dim3(NC, 8), dim3(256), 0, stream>>>(dx, prefix_sig, out + SIG13);
    }
}